// Round 3
// baseline (247.107 us; speedup 1.0000x reference)
//
#include <hip/hip_runtime.h>

// Problem constants (Graphormer node feature + SAGE conv)
#define G_     64
#define NODES_ 511
#define NN_    512          // NODES + 1 (graph token row 0)
#define H_     768
#define E_     4096
#define NTYPE  5            // graph_emb + node_emb[0..3]
#define S_     32           // blocks per graph in fused kernel
#define ROWS_  (NN_ / S_)   // 16 rows per block

typedef float f32x4 __attribute__((ext_vector_type(4)));

// ---------------------------------------------------------------------------
// Kernel 1: projection tables.
//   P_l[t] = emb_t @ W_l^T
//   P_r[t] = emb_t @ W_r^T + b_l     (b_l folded)
// One wave per (m, j): the W row is read ONCE and reused for all 5 embedding
// types (5x less W traffic than wave-per-(m,t,j)). 1536 waves = 192 x 512.
// ---------------------------------------------------------------------------
__global__ __launch_bounds__(512)
void proj_kernel(const float* __restrict__ node_emb,   // (4, H)
                 const float* __restrict__ graph_emb,  // (1, H)
                 const float* __restrict__ W_l,        // (H, H)
                 const float* __restrict__ b_l,        // (H,)
                 const float* __restrict__ W_r,        // (H, H)
                 float* __restrict__ P_l,              // (5, H)
                 float* __restrict__ P_r)              // (5, H)
{
    int wave = blockIdx.x * 8 + (threadIdx.x >> 6);    // 0..1535
    int lane = threadIdx.x & 63;
    int m = wave / H_;                                 // 0 -> W_l, 1 -> W_r
    int j = wave % H_;

    const float* W = ((m == 0) ? W_l : W_r) + (size_t)j * H_;
    int k0 = lane * 4;
    f32x4 w0 = *(const f32x4*)(W + k0);
    f32x4 w1 = *(const f32x4*)(W + k0 + 256);
    f32x4 w2 = *(const f32x4*)(W + k0 + 512);

    float acc[NTYPE];
    #pragma unroll
    for (int t = 0; t < NTYPE; ++t) {
        const float* emb = (t == 0) ? graph_emb : (node_emb + (size_t)(t - 1) * H_);
        f32x4 e0 = *(const f32x4*)(emb + k0);
        f32x4 e1 = *(const f32x4*)(emb + k0 + 256);
        f32x4 e2 = *(const f32x4*)(emb + k0 + 512);
        acc[t] = w0.x*e0.x + w0.y*e0.y + w0.z*e0.z + w0.w*e0.w
               + w1.x*e1.x + w1.y*e1.y + w1.z*e1.z + w1.w*e1.w
               + w2.x*e2.x + w2.y*e2.y + w2.z*e2.z + w2.w*e2.w;
    }
    #pragma unroll
    for (int t = 0; t < NTYPE; ++t) {
        #pragma unroll
        for (int off = 32; off; off >>= 1)
            acc[t] += __shfl_xor(acc[t], off, 64);
    }

    if (lane == 0) {
        if (m == 0) {
            #pragma unroll
            for (int t = 0; t < NTYPE; ++t) P_l[t * H_ + j] = acc[t];
        } else {
            float b = b_l[j];
            #pragma unroll
            for (int t = 0; t < NTYPE; ++t) P_r[t * H_ + j] = acc[t] + b;
        }
    }
}

// ---------------------------------------------------------------------------
// Kernel 2 (fused hist + output): 32 blocks per graph, each owns 16 rows.
// Phase 1: scan this graph's dst stream (16 KB, L2-hit after first block),
//          LDS-histogram only edges landing in our 16 rows (80-int hist).
// Phase 2: per-row coefficients a_t = cnt_t / max(deg,1) and node type -> LDS.
// Phase 3: wave-per-row writes. P_l (5 rows) is preloaded into registers once
//          per thread (15 f32x4); per row only P_r[type] + emb[type] are read
//          from L1.
// Output stores are NONTEMPORAL: round-0 (nt, 225 us) vs round-2 (plain,
// 242 us) A/B shows plain stores regress — the 201 MB zero-reuse output
// stream must stay out of L2 so the L2-resident read set (edges, nodes,
// P tables re-read by 32 blocks/graph) is preserved.
// ---------------------------------------------------------------------------
__global__ __launch_bounds__(256)
void fused_kernel(const int* __restrict__ nodes,       // (G, NODES)
                  const int* __restrict__ edges,       // (G, 2, E)
                  const float* __restrict__ node_emb,  // (4, H)
                  const float* __restrict__ graph_emb, // (1, H)
                  const float* __restrict__ P_l,       // (5, H)
                  const float* __restrict__ P_r,       // (5, H)
                  float* __restrict__ gnf,             // (G, NN, H)
                  float* __restrict__ gef)             // (G, NN, H)
{
    int g  = blockIdx.x >> 5;          // / S_
    int s  = blockIdx.x & (S_ - 1);
    int lo = s * ROWS_;                // first row n handled by this block
    int t  = threadIdx.x;

    __shared__ int   hist[ROWS_ * NTYPE];   // 80 ints
    __shared__ float a_s[ROWS_][NTYPE];     // cnt_t * inv(deg)
    __shared__ int   type_s[ROWS_];

    if (t < ROWS_ * NTYPE) hist[t] = 0;
    __syncthreads();

    const int* eg = edges + (size_t)g * 2 * E_;
    const int* ng = nodes + (size_t)g * NODES_;

    #pragma unroll
    for (int i = 0; i < E_ / 256; ++i) {    // 16 edges per thread
        int e   = t + i * 256;
        int dst = eg[E_ + e];               // coalesced
        unsigned d = (unsigned)(dst - lo);
        if (d < ROWS_) {
            int src  = eg[e];
            int type = (src == 0) ? 0 : (ng[src - 1] + 1);
            atomicAdd(&hist[d * NTYPE + type], 1);
        }
    }
    __syncthreads();

    if (t < ROWS_) {
        float c0 = (float)hist[t * NTYPE + 0];
        float c1 = (float)hist[t * NTYPE + 1];
        float c2 = (float)hist[t * NTYPE + 2];
        float c3 = (float)hist[t * NTYPE + 3];
        float c4 = (float)hist[t * NTYPE + 4];
        float inv = 1.0f / fmaxf(c0 + c1 + c2 + c3 + c4, 1.0f);
        a_s[t][0] = c0 * inv;
        a_s[t][1] = c1 * inv;
        a_s[t][2] = c2 * inv;
        a_s[t][3] = c3 * inv;
        a_s[t][4] = c4 * inv;
        int n = lo + t;
        type_s[t] = (n == 0) ? 0 : (ng[n - 1] + 1);
    }
    __syncthreads();

    // ---- write phase: wave w handles rows {rr*4 + w}, lane covers 3 chunks ----
    int w    = t >> 6;
    int lane = t & 63;
    int k0   = lane * 4;

    // Preload all of P_l into registers: 5 rows x 3 chunks = 15 f32x4.
    f32x4 pl[NTYPE][3];
    #pragma unroll
    for (int tt = 0; tt < NTYPE; ++tt) {
        #pragma unroll
        for (int c = 0; c < 3; ++c)
            pl[tt][c] = *(const f32x4*)(P_l + (size_t)tt * H_ + k0 + c * 256);
    }

    size_t base = ((size_t)g * NN_ + lo) * H_;

    #pragma unroll
    for (int rr = 0; rr < ROWS_ / 4; ++rr) {
        int r  = rr * 4 + w;
        int ty = type_s[r];
        float a0 = a_s[r][0], a1 = a_s[r][1], a2 = a_s[r][2],
              a3 = a_s[r][3], a4 = a_s[r][4];
        const float* prr = P_r + (size_t)ty * H_;
        const float* er  = (ty == 0) ? graph_emb : (node_emb + (size_t)(ty - 1) * H_);
        size_t roff = base + (size_t)r * H_ + k0;

        #pragma unroll
        for (int c = 0; c < 3; ++c) {
            f32x4 pr = *(const f32x4*)(prr + k0 + c * 256);
            f32x4 ev = *(const f32x4*)(er  + k0 + c * 256);
            f32x4 o  = a0 * pl[0][c] + a1 * pl[1][c] + a2 * pl[2][c]
                     + a3 * pl[3][c] + a4 * pl[4][c] + pr;
            __builtin_nontemporal_store(ev, (f32x4*)(gnf + roff + c * 256));
            __builtin_nontemporal_store(o,  (f32x4*)(gef + roff + c * 256));
        }
    }
}

// ---------------------------------------------------------------------------
extern "C" void kernel_launch(void* const* d_in, const int* in_sizes, int n_in,
                              void* d_out, int out_size, void* d_ws, size_t ws_size,
                              hipStream_t stream)
{
    const int*   input_nodes = (const int*)d_in[0];   // (G, NODES) int32
    const int*   input_edges = (const int*)d_in[1];   // (G, 2, E)  int32
    const float* node_emb    = (const float*)d_in[2]; // (4, H)
    const float* graph_emb   = (const float*)d_in[3]; // (1, H)
    const float* W_l         = (const float*)d_in[4]; // (H, H)
    const float* b_l         = (const float*)d_in[5]; // (H,)
    const float* W_r         = (const float*)d_in[6]; // (H, H)

    float* gnf = (float*)d_out;                       // output 0: (G, NN, H)
    float* gef = gnf + (size_t)G_ * NN_ * H_;         // output 1: (G, NN, H)

    float* P_l = (float*)d_ws;                        // 5*H floats
    float* P_r = P_l + NTYPE * H_;                    // 5*H floats

    // Projection tables: 1536 waves (one per (m, j)), 192 blocks x 512.
    proj_kernel<<<(2 * H_) / 8, 512, 0, stream>>>(
        node_emb, graph_emb, W_l, b_l, W_r, P_l, P_r);

    // Fused histogram + outputs: G*S = 2048 blocks x 256 threads.
    fused_kernel<<<G_ * S_, 256, 0, stream>>>(
        input_nodes, input_edges, node_emb, graph_emb, P_l, P_r, gnf, gef);
}

// Round 4
// 228.902 us; speedup vs baseline: 1.0795x; 1.0795x over previous
//
#include <hip/hip_runtime.h>

// Problem constants (Graphormer node feature + SAGE conv)
#define G_     64
#define NODES_ 511
#define NN_    512          // NODES + 1 (graph token row 0)
#define H_     768
#define E_     4096
#define NTYPE  5            // graph_emb + node_emb[0..3]

typedef float f32x4 __attribute__((ext_vector_type(4)));

// ---------------------------------------------------------------------------
// Kernel 1 (fused prep): blocks 0..63  -> per-graph typed in-degree histogram
//                        blocks 64..1023 -> embedding projections
// (Verbatim from the 225.1 us round-0 kernel — known good.)
// ---------------------------------------------------------------------------
__global__ __launch_bounds__(512)
void prep_kernel(const int* __restrict__ edges,      // (G, 2, E)
                 const int* __restrict__ nodes,      // (G, NODES)
                 const float* __restrict__ node_emb, // (4, H)
                 const float* __restrict__ graph_emb,// (1, H)
                 const float* __restrict__ W_l,      // (H, H)
                 const float* __restrict__ b_l,      // (H,)
                 const float* __restrict__ W_r,      // (H, H)
                 int* __restrict__ cnt,              // (G, NN, 5)
                 float* __restrict__ P_l,            // (5, H)
                 float* __restrict__ P_r)            // (5, H)
{
    if (blockIdx.x < G_) {
        // ----- count phase: one block per graph -----
        __shared__ int hist[NN_ * NTYPE];              // 10 KB
        int g = blockIdx.x;
        int t = threadIdx.x;

        #pragma unroll
        for (int i = 0; i < NN_ * NTYPE / 512; ++i)    // 5 per thread
            hist[t + i * 512] = 0;
        __syncthreads();

        const int* eg = edges + (size_t)g * 2 * E_;
        const int* ng = nodes + (size_t)g * NODES_;
        #pragma unroll
        for (int i = 0; i < E_ / 512; ++i) {           // 8 edges per thread
            int e = t + i * 512;
            int src = eg[e];
            int dst = eg[E_ + e];
            int type = (src == 0) ? 0 : (ng[src - 1] + 1);
            atomicAdd(&hist[dst * NTYPE + type], 1);
        }
        __syncthreads();

        int* cg = cnt + (size_t)g * NN_ * NTYPE;
        #pragma unroll
        for (int i = 0; i < NN_ * NTYPE / 512; ++i)    // coalesced 10 KB store
            cg[t + i * 512] = hist[t + i * 512];
    } else {
        // ----- proj phase: 960 blocks x 8 waves = 7680 waves -----
        int wave = (blockIdx.x - G_) * 8 + (threadIdx.x >> 6);
        int lane = threadIdx.x & 63;
        int m = wave / (NTYPE * H_);     // 0 -> W_l, 1 -> W_r
        int r = wave % (NTYPE * H_);
        int t = r / H_;
        int j = r % H_;
        const float* emb = (t == 0) ? graph_emb : (node_emb + (size_t)(t - 1) * H_);
        const float* W   = ((m == 0) ? W_l : W_r) + (size_t)j * H_;

        float a0, a1, a2;
        {
            int k0 = lane * 4;
            f32x4 w0 = *(const f32x4*)(W + k0);
            f32x4 e0 = *(const f32x4*)(emb + k0);
            f32x4 w1 = *(const f32x4*)(W + k0 + 256);
            f32x4 e1 = *(const f32x4*)(emb + k0 + 256);
            f32x4 w2 = *(const f32x4*)(W + k0 + 512);
            f32x4 e2 = *(const f32x4*)(emb + k0 + 512);
            a0 = w0.x * e0.x + w0.y * e0.y + w0.z * e0.z + w0.w * e0.w;
            a1 = w1.x * e1.x + w1.y * e1.y + w1.z * e1.z + w1.w * e1.w;
            a2 = w2.x * e2.x + w2.y * e2.y + w2.z * e2.z + w2.w * e2.w;
        }
        float acc = a0 + a1 + a2;
        #pragma unroll
        for (int off = 32; off; off >>= 1)
            acc += __shfl_xor(acc, off, 64);

        if (lane == 0) {
            if (m == 0) P_l[t * H_ + j] = acc;
            else        P_r[t * H_ + j] = acc + b_l[j];
        }
    }
}

// ---------------------------------------------------------------------------
// Kernel 2 (wave-per-row writes): one wave owns 4 consecutive (g,n) rows.
//  - P_l preloaded into 15 f32x4 registers ONCE per thread, amortized over
//    4 rows x 6 store instructions (the R0 thread-per-float4 version re-read
//    5 P_l vectors from L1 for every 2 stores -> 3x the L1 traffic).
//  - Per-row scalars (nodes type, 5 cnt values, rcp) computed once per wave
//    via same-address broadcast loads instead of once per 192 threads.
//  - 2048 blocks x 256: all 8192 waves co-resident, steady store stream.
//  - nt stores kept (matches the 225 us baseline; R2/R3 shows nt≈plain).
// ---------------------------------------------------------------------------
__global__ __launch_bounds__(256)
void out_kernel(const int* __restrict__ nodes,     // (G, NODES)
                const int* __restrict__ cnt,       // (G, NN, 5)
                const float* __restrict__ node_emb,
                const float* __restrict__ graph_emb,
                const float* __restrict__ P_l,
                const float* __restrict__ P_r,
                float* __restrict__ gnf,           // (G, NN, H)
                float* __restrict__ gef)           // (G, NN, H)
{
    int wave = blockIdx.x * 4 + (threadIdx.x >> 6);   // 0..8191
    int lane = threadIdx.x & 63;
    int k0   = lane * 4;

    // Preload all of P_l into registers: 5 rows x 3 chunks = 15 f32x4.
    f32x4 pl[NTYPE][3];
    #pragma unroll
    for (int t = 0; t < NTYPE; ++t) {
        #pragma unroll
        for (int c = 0; c < 3; ++c)
            pl[t][c] = *(const f32x4*)(P_l + (size_t)t * H_ + k0 + c * 256);
    }

    int row0 = wave * 4;                              // 4 rows per wave
    #pragma unroll
    for (int i = 0; i < 4; ++i) {
        int row = row0 + i;
        int g = row >> 9;                             // NN = 512
        int n = row & (NN_ - 1);

        int ty = (n == 0) ? 0 : (nodes[g * NODES_ + n - 1] + 1);

        const int* c = cnt + (size_t)row * NTYPE;
        float c0 = (float)c[0], c1 = (float)c[1], c2 = (float)c[2],
              c3 = (float)c[3], c4 = (float)c[4];
        float inv = 1.0f / fmaxf(c0 + c1 + c2 + c3 + c4, 1.0f);
        float a0 = c0 * inv, a1 = c1 * inv, a2 = c2 * inv,
              a3 = c3 * inv, a4 = c4 * inv;

        const float* prr = P_r + (size_t)ty * H_;
        const float* er  = (ty == 0) ? graph_emb : (node_emb + (size_t)(ty - 1) * H_);
        size_t roff = (size_t)row * H_ + k0;

        #pragma unroll
        for (int ch = 0; ch < 3; ++ch) {
            f32x4 pr = *(const f32x4*)(prr + k0 + ch * 256);
            f32x4 ev = *(const f32x4*)(er  + k0 + ch * 256);
            f32x4 o  = a0 * pl[0][ch] + a1 * pl[1][ch] + a2 * pl[2][ch]
                     + a3 * pl[3][ch] + a4 * pl[4][ch] + pr;
            __builtin_nontemporal_store(ev, (f32x4*)(gnf + roff + ch * 256));
            __builtin_nontemporal_store(o,  (f32x4*)(gef + roff + ch * 256));
        }
    }
}

// ---------------------------------------------------------------------------
extern "C" void kernel_launch(void* const* d_in, const int* in_sizes, int n_in,
                              void* d_out, int out_size, void* d_ws, size_t ws_size,
                              hipStream_t stream)
{
    const int*   input_nodes = (const int*)d_in[0];   // (G, NODES) int32
    const int*   input_edges = (const int*)d_in[1];   // (G, 2, E)  int32
    const float* node_emb    = (const float*)d_in[2]; // (4, H)
    const float* graph_emb   = (const float*)d_in[3]; // (1, H)
    const float* W_l         = (const float*)d_in[4]; // (H, H)
    const float* b_l         = (const float*)d_in[5]; // (H,)
    const float* W_r         = (const float*)d_in[6]; // (H, H)

    float* gnf = (float*)d_out;                        // output 0: (G, NN, H)
    float* gef = gnf + (size_t)G_ * NN_ * H_;          // output 1: (G, NN, H)

    int*   cnt = (int*)d_ws;                                    // G*NN*5 ints = 2.62 MB
    size_t cnt_bytes = (size_t)G_ * NN_ * NTYPE * sizeof(int);
    float* P_l = (float*)((char*)d_ws + cnt_bytes);             // 5*H floats
    float* P_r = P_l + NTYPE * H_;                              // 5*H floats

    // Fused count+proj: 64 count blocks + 960 proj blocks, 512 threads each.
    prep_kernel<<<G_ + (2 * NTYPE * H_) / 8, 512, 0, stream>>>(
        input_edges, input_nodes, node_emb, graph_emb, W_l, b_l, W_r,
        cnt, P_l, P_r);

    // Wave-per-row writes: 32768 rows / 4 rows-per-wave = 8192 waves = 2048 blocks.
    out_kernel<<<(G_ * NN_) / 16, 256, 0, stream>>>(
        input_nodes, cnt, node_emb, graph_emb, P_l, P_r, gnf, gef);
}

// Round 5
// 215.112 us; speedup vs baseline: 1.1487x; 1.0641x over previous
//
#include <hip/hip_runtime.h>

// Problem constants (Graphormer node feature + SAGE conv)
#define G_     64
#define NODES_ 511
#define NN_    512          // NODES + 1 (graph token row 0)
#define H_     768
#define E_     4096
#define NTYPE  5            // graph_emb + node_emb[0..3]

#define PROJB_ 960          // proj blocks (7680 waves)
#define GNFB_  2048         // gnf-writer blocks inside prep

typedef float f32x4 __attribute__((ext_vector_type(4)));

// ---------------------------------------------------------------------------
// Kernel 1 (3-phase prep):
//   blocks [0,64)            : per-graph typed in-degree histogram -> packed
//                              per-row params {a0..a4, type} (replaces cnt;
//                              kills the div + nodes-load in the gef kernel)
//   blocks [64, 64+960)      : projection tables P_l / P_r (verbatim R0 proj)
//   blocks [1024, 1024+2048) : gnf writer. gnf depends ONLY on nodes+emb, so
//                              these blocks stream 100.7 MB of stores while
//                              the count/proj blocks compute — filling store
//                              pipes that were previously idle during prep.
// ---------------------------------------------------------------------------
__global__ __launch_bounds__(512)
void prep_kernel(const int* __restrict__ edges,      // (G, 2, E)
                 const int* __restrict__ nodes,      // (G, NODES)
                 const float* __restrict__ node_emb, // (4, H)
                 const float* __restrict__ graph_emb,// (1, H)
                 const float* __restrict__ W_l,      // (H, H)
                 const float* __restrict__ b_l,      // (H,)
                 const float* __restrict__ W_r,      // (H, H)
                 float* __restrict__ params,         // (G, NN, 8): a0..a4,type,-,-
                 float* __restrict__ P_l,            // (5, H)
                 float* __restrict__ P_r,            // (5, H)
                 float* __restrict__ gnf)            // (G, NN, H)
{
    int t = threadIdx.x;
    if (blockIdx.x < G_) {
        // ----- count phase: one block per graph -----
        __shared__ int hist[NN_ * NTYPE];              // 10 KB
        int g = blockIdx.x;

        #pragma unroll
        for (int i = 0; i < NN_ * NTYPE / 512; ++i)    // 5 per thread
            hist[t + i * 512] = 0;
        __syncthreads();

        const int* eg = edges + (size_t)g * 2 * E_;
        const int* ng = nodes + (size_t)g * NODES_;
        #pragma unroll
        for (int i = 0; i < E_ / 512; ++i) {           // 8 edges per thread
            int e = t + i * 512;
            int src = eg[e];
            int dst = eg[E_ + e];
            int type = (src == 0) ? 0 : (ng[src - 1] + 1);
            atomicAdd(&hist[dst * NTYPE + type], 1);
        }
        __syncthreads();

        // one row per thread: emit packed params {a0..a4, type}
        {
            int n = t;                                 // 512 rows, 512 threads
            float c0 = (float)hist[n * NTYPE + 0];
            float c1 = (float)hist[n * NTYPE + 1];
            float c2 = (float)hist[n * NTYPE + 2];
            float c3 = (float)hist[n * NTYPE + 3];
            float c4 = (float)hist[n * NTYPE + 4];
            float inv = 1.0f / fmaxf(c0 + c1 + c2 + c3 + c4, 1.0f);
            int ty = (n == 0) ? 0 : (ng[n - 1] + 1);
            f32x4 v0 = {c0 * inv, c1 * inv, c2 * inv, c3 * inv};
            f32x4 v1 = {c4 * inv, __int_as_float(ty), 0.0f, 0.0f};
            float* pp = params + ((size_t)g * NN_ + n) * 8;
            *(f32x4*)pp       = v0;
            *(f32x4*)(pp + 4) = v1;
        }
    } else if (blockIdx.x < G_ + PROJB_) {
        // ----- proj phase: 960 blocks x 8 waves = 7680 waves -----
        int wave = (blockIdx.x - G_) * 8 + (t >> 6);
        int lane = t & 63;
        int m = wave / (NTYPE * H_);     // 0 -> W_l, 1 -> W_r
        int r = wave % (NTYPE * H_);
        int ty = r / H_;
        int j = r % H_;
        const float* emb = (ty == 0) ? graph_emb : (node_emb + (size_t)(ty - 1) * H_);
        const float* W   = ((m == 0) ? W_l : W_r) + (size_t)j * H_;

        float a0, a1, a2;
        {
            int k0 = lane * 4;
            f32x4 w0 = *(const f32x4*)(W + k0);
            f32x4 e0 = *(const f32x4*)(emb + k0);
            f32x4 w1 = *(const f32x4*)(W + k0 + 256);
            f32x4 e1 = *(const f32x4*)(emb + k0 + 256);
            f32x4 w2 = *(const f32x4*)(W + k0 + 512);
            f32x4 e2 = *(const f32x4*)(emb + k0 + 512);
            a0 = w0.x * e0.x + w0.y * e0.y + w0.z * e0.z + w0.w * e0.w;
            a1 = w1.x * e1.x + w1.y * e1.y + w1.z * e1.z + w1.w * e1.w;
            a2 = w2.x * e2.x + w2.y * e2.y + w2.z * e2.z + w2.w * e2.w;
        }
        float acc = a0 + a1 + a2;
        #pragma unroll
        for (int off = 32; off; off >>= 1)
            acc += __shfl_xor(acc, off, 64);

        if (lane == 0) {
            if (m == 0) P_l[ty * H_ + j] = acc;
            else        P_r[ty * H_ + j] = acc + b_l[j];
        }
    } else {
        // ----- gnf writer: 2048 blocks x 8 waves, 2 rows per wave -----
        int wv   = (blockIdx.x - (G_ + PROJB_)) * 8 + (t >> 6);  // 0..16383
        int lane = t & 63;
        int k0   = lane * 4;
        #pragma unroll
        for (int i = 0; i < 2; ++i) {
            int row = wv * 2 + i;
            int g = row >> 9;                          // NN = 512
            int n = row & (NN_ - 1);
            int ty = (n == 0) ? 0 : (nodes[g * NODES_ + n - 1] + 1);
            const float* er = (ty == 0) ? graph_emb
                                        : (node_emb + (size_t)(ty - 1) * H_);
            size_t roff = (size_t)row * H_ + k0;
            #pragma unroll
            for (int c = 0; c < 3; ++c) {
                f32x4 ev = *(const f32x4*)(er + k0 + c * 256);
                *(f32x4*)(gnf + roff + c * 256) = ev;
            }
        }
    }
}

// ---------------------------------------------------------------------------
// Kernel 2 (gef only): one wave owns 4 rows. Per row: 2 broadcast param
// loads + 3 P_r loads + 3 FMA chunks + 3 stores — half of R4's out kernel
// (gnf already written by prep). P_l preloaded into 15 f32x4 registers.
// ---------------------------------------------------------------------------
__global__ __launch_bounds__(256)
void gef_kernel(const float* __restrict__ params,  // (G, NN, 8)
                const float* __restrict__ P_l,     // (5, H)
                const float* __restrict__ P_r,     // (5, H)
                float* __restrict__ gef)           // (G, NN, H)
{
    int wave = blockIdx.x * 4 + (threadIdx.x >> 6);   // 0..8191
    int lane = threadIdx.x & 63;
    int k0   = lane * 4;

    f32x4 pl[NTYPE][3];
    #pragma unroll
    for (int tt = 0; tt < NTYPE; ++tt) {
        #pragma unroll
        for (int c = 0; c < 3; ++c)
            pl[tt][c] = *(const f32x4*)(P_l + (size_t)tt * H_ + k0 + c * 256);
    }

    int row0 = wave * 4;                              // 4 rows per wave
    #pragma unroll
    for (int i = 0; i < 4; ++i) {
        int row = row0 + i;
        const float* pp = params + (size_t)row * 8;   // wave-uniform -> broadcast
        f32x4 v0 = *(const f32x4*)pp;
        f32x4 v1 = *(const f32x4*)(pp + 4);
        int ty = __float_as_int(v1.y);
        const float* prr = P_r + (size_t)ty * H_;
        size_t roff = (size_t)row * H_ + k0;

        #pragma unroll
        for (int c = 0; c < 3; ++c) {
            f32x4 pr = *(const f32x4*)(prr + k0 + c * 256);
            f32x4 o  = v0.x * pl[0][c] + v0.y * pl[1][c] + v0.z * pl[2][c]
                     + v0.w * pl[3][c] + v1.x * pl[4][c] + pr;
            *(f32x4*)(gef + roff + c * 256) = o;
        }
    }
}

// ---------------------------------------------------------------------------
extern "C" void kernel_launch(void* const* d_in, const int* in_sizes, int n_in,
                              void* d_out, int out_size, void* d_ws, size_t ws_size,
                              hipStream_t stream)
{
    const int*   input_nodes = (const int*)d_in[0];   // (G, NODES) int32
    const int*   input_edges = (const int*)d_in[1];   // (G, 2, E)  int32
    const float* node_emb    = (const float*)d_in[2]; // (4, H)
    const float* graph_emb   = (const float*)d_in[3]; // (1, H)
    const float* W_l         = (const float*)d_in[4]; // (H, H)
    const float* b_l         = (const float*)d_in[5]; // (H,)
    const float* W_r         = (const float*)d_in[6]; // (H, H)

    float* gnf = (float*)d_out;                        // output 0: (G, NN, H)
    float* gef = gnf + (size_t)G_ * NN_ * H_;          // output 1: (G, NN, H)

    float* params = (float*)d_ws;                      // G*NN*8 floats = 1 MB
    float* P_l = params + (size_t)G_ * NN_ * 8;        // 5*H floats
    float* P_r = P_l + NTYPE * H_;                     // 5*H floats

    // Prep: 64 count + 960 proj + 2048 gnf-writer blocks, 512 threads each.
    prep_kernel<<<G_ + PROJB_ + GNFB_, 512, 0, stream>>>(
        input_edges, input_nodes, node_emb, graph_emb, W_l, b_l, W_r,
        params, P_l, P_r, gnf);

    // gef: 32768 rows / 4 rows-per-wave = 8192 waves = 2048 blocks x 256.
    gef_kernel<<<(G_ * NN_) / 16, 256, 0, stream>>>(
        params, P_l, P_r, gef);
}